// Round 5
// baseline (175.092 us; speedup 1.0000x reference)
//
#include <hip/hip_runtime.h>
#include <hip/hip_bf16.h>

typedef unsigned short u16;
typedef _Float16 f16;
typedef __attribute__((ext_vector_type(8))) short s16x8;
typedef __attribute__((ext_vector_type(8))) _Float16 f16x8;
typedef __attribute__((ext_vector_type(4))) float f32x4;
typedef __attribute__((ext_vector_type(4))) unsigned short u16x4;

// ---------------- MFMA wrapper (f16) ----------------
template <typename T>
__device__ __forceinline__ auto mfma_try(T a, T b, f32x4 c, int)
    -> decltype(__builtin_amdgcn_mfma_f32_16x16x32_f16(a, b, c, 0, 0, 0)) {
  return __builtin_amdgcn_mfma_f32_16x16x32_f16(a, b, c, 0, 0, 0);
}
template <typename T>
__device__ __forceinline__ f32x4 mfma_try(T a, T b, f32x4 c, long) {
  return __builtin_amdgcn_mfma_f32_16x16x32_f16(
      __builtin_bit_cast(f16x8, a), __builtin_bit_cast(f16x8, b), c, 0, 0, 0);
}
__device__ __forceinline__ f32x4 MFMA16(s16x8 a, s16x8 b, f32x4 c) {
  return mfma_try(a, b, c, 0);
}

__device__ __forceinline__ void gload16(const void* g, void* s) {
  __builtin_amdgcn_global_load_lds(
      (const __attribute__((address_space(1))) void*)g,
      (__attribute__((address_space(3))) void*)s, 16, 0, 0);
}

__device__ __forceinline__ u16 f2h(float x) {
  f16 h = (f16)x;
  u16 u;
  __builtin_memcpy(&u, &h, 2);
  return u;
}
__device__ __forceinline__ float h2f(u16 u) {
  f16 h;
  __builtin_memcpy(&h, &u, 2);
  return (float)h;
}

#define LDS_SWZ(r, cb) ((cb) ^ (((r)&7) << 4))

__device__ __forceinline__ void bar() { __builtin_amdgcn_s_barrier(); }
// rule 18: inline-asm lgkmcnt needs a following sched_barrier(0)
__device__ __forceinline__ void lgkm0() {
  asm volatile("s_waitcnt lgkmcnt(0)" ::: "memory");
  __builtin_amdgcn_sched_barrier(0);
}

// =============== 256x256x64 8-wave 4-phase core, deep prefetch =============
// LDS: 2 bufs x [A-h0|A-h1|B-h0|B-h1] x 16KB = 128KB. Halves [128][64] f16,
// row-swizzled via pre-swizzled global source (rule 21). Waves 2M x 4N,
// per-wave output 128x64.
// Pipeline invariant: during step t (buffer p=t&1), phases 2-3 stage step
// t+2's tiles into buf[p] itself (all buf[p] reads end at phase 1). So each
// load has >=4 phases (~800cy) of cover; vmcnt(8) once per step drains
// exactly the t+1 batch while t+2's 8 loads stay in flight.
template <int P>
__device__ __forceinline__ void k_step(
    const u16* __restrict__ Apan, int lda, const u16* __restrict__ Bpan,
    int ldb, int t, int NS, char* lds, int l, int w, int wr, int wc, int sr,
    int scol, f32x4 (&acc)[8][4]) {
  constexpr int BUF = P << 16;
  s16x8 af[8][2], bf[4][2];
  auto rdA = [&](int m, int ks) -> s16x8 {
    int r = m * 16 + (l & 15);
    int cb = ks * 64 + ((l >> 4) << 4);
    return *(const s16x8*)(lds + BUF + wr * 16384 + r * 128 + LDS_SWZ(r, cb));
  };
  auto rdB = [&](int n, int ks) -> s16x8 {
    int row = wc * 64 + n * 16 + (l & 15);
    int r = row & 127;
    int cb = ks * 64 + ((l >> 4) << 4);
    return *(const s16x8*)(lds + BUF + 32768 + (wc >> 1) * 16384 + r * 128 +
                           LDS_SWZ(r, cb));
  };
  auto stageH = [&](const u16* pan, int ld, int tt, int h, int region) {
    char* dst = lds + BUF + region * 16384 + (w << 10);  // buf[(t+2)&1]==buf[P]
    const u16* src = pan + (long)(h * 128 + sr) * ld + tt * 64 + scol;
    gload16(src, dst);
    gload16(src + (long)64 * ld, dst + 8192);
  };
  auto mfma2 = [&](int mb) {
#pragma unroll
    for (int m = mb; m < mb + 2; ++m)
#pragma unroll
      for (int n = 0; n < 4; ++n) {
        acc[m][n] = MFMA16(af[m][0], bf[n][0], acc[m][n]);
        acc[m][n] = MFMA16(af[m][1], bf[n][1], acc[m][n]);
      }
  };
  // ---- phase 0: read all B (8) + A m0,m1 (4); MFMA m0,m1
#pragma unroll
  for (int n = 0; n < 4; ++n) { bf[n][0] = rdB(n, 0); bf[n][1] = rdB(n, 1); }
#pragma unroll
  for (int m = 0; m < 2; ++m) { af[m][0] = rdA(m, 0); af[m][1] = rdA(m, 1); }
  asm volatile("s_waitcnt lgkmcnt(8)" ::: "memory");  // throttle (12 issued)
  bar(); lgkm0();
  __builtin_amdgcn_s_setprio(1); mfma2(0); __builtin_amdgcn_s_setprio(0);
  bar();
  // ---- phase 1: read A m2..m7 (12); MFMA m2,m3
#pragma unroll
  for (int m = 2; m < 8; ++m) { af[m][0] = rdA(m, 0); af[m][1] = rdA(m, 1); }
  asm volatile("s_waitcnt lgkmcnt(8)" ::: "memory");
  bar(); lgkm0();
  __builtin_amdgcn_s_setprio(1); mfma2(2); __builtin_amdgcn_s_setprio(0);
  bar();
  // ---- phase 2: stage t+2 A-h0,B-h0 into buf[P] (all buf[P] reads done)
  if (t + 2 < NS) {
    stageH(Apan, lda, t + 2, 0, 0);
    stageH(Bpan, ldb, t + 2, 0, 2);
  }
  bar();
  __builtin_amdgcn_s_setprio(1); mfma2(4); __builtin_amdgcn_s_setprio(0);
  bar();
  // ---- phase 3: stage t+2 A-h1,B-h1; counted vmcnt; MFMA m6,m7
  if (t + 2 < NS) {
    stageH(Apan, lda, t + 2, 1, 1);
    stageH(Bpan, ldb, t + 2, 1, 3);
    asm volatile("s_waitcnt vmcnt(8)" ::: "memory");  // t+1 batch done
  } else {
    asm volatile("s_waitcnt vmcnt(0)" ::: "memory");  // tail: drain all
  }
  bar();
  __builtin_amdgcn_s_setprio(1); mfma2(6); __builtin_amdgcn_s_setprio(0);
  bar();
}

__device__ __forceinline__ void gemm256_core(const u16* __restrict__ Apan,
                                             int lda,
                                             const u16* __restrict__ Bpan,
                                             int ldb, char* lds,
                                             f32x4 (&acc)[8][4]) {
  const int tid = threadIdx.x;
  const int w = tid >> 6, l = tid & 63;
  const int wr = w >> 2, wc = w & 3;
  const int sr = tid >> 3;
  const int scol = (((tid & 7) * 16) ^ ((sr & 7) << 4)) >> 1;
  constexpr int NS = 16;  // K = 1024
  auto stageP = [&](const u16* pan, int ld, int t, int h, int region) {
    char* dst = lds + ((t & 1) << 16) + region * 16384 + (w << 10);
    const u16* src = pan + (long)(h * 128 + sr) * ld + t * 64 + scol;
    gload16(src, dst);
    gload16(src + (long)64 * ld, dst + 8192);
  };
  // prologue: stage steps 0 and 1 (8 loads each); wait step0 resident.
  stageP(Apan, lda, 0, 0, 0); stageP(Apan, lda, 0, 1, 1);
  stageP(Bpan, ldb, 0, 0, 2); stageP(Bpan, ldb, 0, 1, 3);
  stageP(Apan, lda, 1, 0, 0); stageP(Apan, lda, 1, 1, 1);
  stageP(Bpan, ldb, 1, 0, 2); stageP(Bpan, ldb, 1, 1, 3);
  asm volatile("s_waitcnt vmcnt(8)" ::: "memory");
  bar();
  for (int t = 0; t < NS; t += 2) {
    k_step<0>(Apan, lda, Bpan, ldb, t, NS, lds, l, w, wr, wc, sr, scol, acc);
    k_step<1>(Apan, lda, Bpan, ldb, t + 1, NS, lds, l, w, wr, wc, sr, scol, acc);
  }
}

// merged projections on the 256^2 core: y=0 K, y=1 Q, y=2 V^T.
__global__ __launch_bounds__(512, 2) void proj256_kernel(
    const u16* __restrict__ xk, const u16* __restrict__ xq, const u16* __restrict__ xv,
    const u16* __restrict__ wk, const u16* __restrict__ wq, const u16* __restrict__ wv,
    u16* __restrict__ K, u16* __restrict__ Q, u16* __restrict__ Vt) {
  __shared__ char lds[131072];
  const int y = blockIdx.y;
  const u16* X = y == 0 ? xk : (y == 1 ? xq : xv);
  const u16* W = y == 0 ? wk : (y == 1 ? wq : wv);
  const int bx = blockIdx.x;
  const int swz = (bx & 7) * 16 + (bx >> 3);  // 128 blocks, bijective
  const int tm = swz >> 2, tn = swz & 3;      // 32 x 4 tiles of 256
  f32x4 acc[8][4] = {};
  gemm256_core(X + (long)tm * 256 * 1024, 1024, W + (long)tn * 256 * 1024, 1024,
               lds, acc);
  const int l = threadIdx.x & 63, w = threadIdx.x >> 6;
  const int wr = w >> 2, wc = w & 3;
  const int rg0 = tm * 256 + wr * 128, cg0 = tn * 256 + wc * 64;
  if (y < 2) {
    u16* C = y == 0 ? K : Q;
#pragma unroll
    for (int m = 0; m < 8; ++m)
#pragma unroll
      for (int n = 0; n < 4; ++n)
#pragma unroll
        for (int j = 0; j < 4; ++j) {
          int rg = rg0 + m * 16 + ((l >> 4) << 2) + j;
          int cg = cg0 + n * 16 + (l & 15);
          C[(long)rg * 1024 + cg] = f2h(acc[m][n][j]);
        }
  } else {
#pragma unroll
    for (int m = 0; m < 8; ++m) {
      int rg = rg0 + m * 16 + ((l >> 4) << 2);
      int b = rg >> 11, rl = rg & 2047;
#pragma unroll
      for (int n = 0; n < 4; ++n) {
        int cg = cg0 + n * 16 + (l & 15);
        u16x4 pk;
#pragma unroll
        for (int j = 0; j < 4; ++j) pk[j] = f2h(acc[m][n][j]);
        *(u16x4*)(Vt + (long)b * (1024 * 2048) + (long)cg * 2048 + rl) = pk;
      }
    }
  }
}

// =============== 128x128x64 2-phase core (qkt, pv) =========================
struct Geom {
  int srow[4], scol[4];
  int w, l, wr, wc;
};

__device__ __forceinline__ Geom make_geom() {
  Geom g;
  int tid = threadIdx.x;
  g.w = tid >> 6; g.l = tid & 63;
  g.wr = g.w >> 1; g.wc = g.w & 1;
#pragma unroll
  for (int i = 0; i < 4; ++i) {
    int off = i * 4096 + g.w * 1024 + g.l * 16;
    int r = off >> 7, cb = off & 127;
    g.srow[i] = r;
    g.scol[i] = LDS_SWZ(r, cb) >> 1;
  }
  return g;
}

__device__ __forceinline__ void stage(const u16* pan, int ld, int k0,
                                      char* lds, const Geom& g) {
#pragma unroll
  for (int i = 0; i < 4; ++i)
    gload16(pan + (long)g.srow[i] * ld + k0 + g.scol[i],
            lds + i * 4096 + g.w * 1024);
}

__device__ __forceinline__ void compute_step(const char* lA, const char* lB,
                                             const Geom& g, f32x4 acc[4][4]) {
#pragma unroll
  for (int ks = 0; ks < 2; ++ks) {
    s16x8 af[4], bg[4];
#pragma unroll
    for (int m = 0; m < 4; ++m) {
      int r = g.wr * 64 + m * 16 + (g.l & 15);
      int cb = ks * 64 + ((g.l >> 4) << 4);
      af[m] = *(const s16x8*)(lA + r * 128 + LDS_SWZ(r, cb));
    }
#pragma unroll
    for (int n = 0; n < 4; ++n) {
      int r = g.wc * 64 + n * 16 + (g.l & 15);
      int cb = ks * 64 + ((g.l >> 4) << 4);
      bg[n] = *(const s16x8*)(lB + r * 128 + LDS_SWZ(r, cb));
    }
#pragma unroll
    for (int m = 0; m < 4; ++m)
#pragma unroll
      for (int n = 0; n < 4; ++n)
        acc[m][n] = MFMA16(af[m], bg[n], acc[m][n]);
  }
}

__device__ __forceinline__ void gemm_core(const u16* Apan, int lda,
                                          const u16* Bpan, int ldb, int nsteps,
                                          char* lA, char* lB, const Geom& g,
                                          f32x4 acc[4][4]) {
  stage(Apan, lda, 0, lA, g);
  stage(Bpan, ldb, 0, lB, g);
  __syncthreads();
  for (int t = 0; t < nsteps; ++t) {
    int cur = (t & 1) << 14;
    if (t + 1 < nsteps) {
      int nxt = ((t + 1) & 1) << 14;
      stage(Apan, lda, (t + 1) * 64, lA + nxt, g);
      stage(Bpan, ldb, (t + 1) * 64, lB + nxt, g);
    }
    compute_step(lA + cur, lB + cur, g, acc);
    if (t + 1 < nsteps) __syncthreads();
  }
}

// scores = Q K^T, triangular tile grid, f16 out. 544 blocks.
__global__ __launch_bounds__(256, 2) void qkt_kernel(
    const u16* __restrict__ Q, const u16* __restrict__ K, u16* __restrict__ S) {
  __shared__ char lds[65536];
  const int bx = blockIdx.x;
  const int swz = (bx & 7) * 68 + (bx >> 3);  // 544 = 8*68, bijective
  const int b = swz / 136;
  int t = swz - b * 136;
  int tm = 0;
  while (t > tm) { t -= tm + 1; ++tm; }
  const int tn = t;
  Geom g = make_geom();
  f32x4 acc[4][4] = {};
  const u16* Qb = Q + (long)b * 2048 * 1024;
  const u16* Kb = K + (long)b * 2048 * 1024;
  gemm_core(Qb + (long)tm * 128 * 1024, 1024, Kb + (long)tn * 128 * 1024, 1024,
            16, lds, lds + 32768, g, acc);
  u16* Sb = S + (long)b * 2048 * 2048;
  const int rg0 = tm * 128 + g.wr * 64, cg0 = tn * 128 + g.wc * 64;
#pragma unroll
  for (int m = 0; m < 4; ++m)
#pragma unroll
    for (int n = 0; n < 4; ++n)
#pragma unroll
      for (int j = 0; j < 4; ++j) {
        int rg = rg0 + m * 16 + ((g.l >> 4) << 2) + j;
        int cg = cg0 + n * 16 + (g.l & 15);
        Sb[(long)rg * 2048 + cg] = f2h(acc[m][n][j]);
      }
}

// O = P V (k-limited), f32 out. 512 blocks.
__global__ __launch_bounds__(256, 2) void pv_kernel(
    const u16* __restrict__ P, const u16* __restrict__ Vt, float* __restrict__ O) {
  __shared__ char lds[65536];
  const int bx = blockIdx.x;
  const int swz = (bx & 7) * 64 + (bx >> 3);
  const int b = swz >> 7, loc = swz & 127;
  const int tm = loc >> 3, tn = loc & 7;
  Geom g = make_geom();
  f32x4 acc[4][4] = {};
  gemm_core(P + ((long)b * 2048 + tm * 128) * 2048, 2048,
            Vt + (long)b * 1024 * 2048 + (long)tn * 128 * 2048, 2048,
            (tm + 1) * 2, lds, lds + 32768, g, acc);
  const int rg0 = tm * 128 + g.wr * 64, cg0 = tn * 128 + g.wc * 64;
#pragma unroll
  for (int m = 0; m < 4; ++m)
#pragma unroll
    for (int n = 0; n < 4; ++n)
#pragma unroll
      for (int j = 0; j < 4; ++j) {
        int rg = rg0 + m * 16 + ((g.l >> 4) << 2) + j;
        int cg = cg0 + n * 16 + (g.l & 15);
        O[((long)b * 2048 + rg) * 1024 + cg] = acc[m][n][j];
      }
}

// ---------------- causal softmax: f16 scores -> f16 P ----------------
__global__ __launch_bounds__(256) void softmax_causal(
    const u16* __restrict__ S, u16* __restrict__ P) {
  const int row = blockIdx.x;  // b*2048 + i
  const int i_q = row & 2047;
  const u16* sr = S + (long)row * 2048;
  u16* pr = P + (long)row * 2048;
  const int tid = threadIdx.x;
  const int l = tid & 63, w = tid >> 6;
  const int base = tid * 8;

  s16x8 raw = *(const s16x8*)(sr + base);
  float v[8];
  float m = -INFINITY;
#pragma unroll
  for (int j = 0; j < 8; ++j) {
    float x = h2f((u16)raw[j]);
    x = (base + j <= i_q) ? x : -INFINITY;  // mask BEFORE any use
    v[j] = x;
    m = fmaxf(m, x);
  }
  __shared__ float red[8];
  for (int o = 32; o; o >>= 1) m = fmaxf(m, __shfl_xor(m, o, 64));
  if (l == 0) red[w] = m;
  __syncthreads();
  m = fmaxf(fmaxf(red[0], red[1]), fmaxf(red[2], red[3]));

  float s = 0.f;
#pragma unroll
  for (int j = 0; j < 8; ++j) {
    v[j] = expf(v[j] - m);
    s += v[j];
  }
  for (int o = 32; o; o >>= 1) s += __shfl_xor(s, o, 64);
  if (l == 0) red[4 + w] = s;
  __syncthreads();
  s = (red[4] + red[5]) + (red[6] + red[7]);
  float inv = 1.0f / s;

  s16x8 o;
#pragma unroll
  for (int j = 0; j < 8; ++j) o[j] = (short)f2h(v[j] * inv);
  *(s16x8*)(pr + base) = o;
}

// ---------------- casts ----------------
__global__ __launch_bounds__(256) void xcast_kernel(
    const float* __restrict__ x0, const float* __restrict__ x1,
    const float* __restrict__ x2, u16* __restrict__ o0, u16* __restrict__ o1,
    u16* __restrict__ o2) {
  const int y = blockIdx.y;
  const float* in = y == 0 ? x0 : (y == 1 ? x1 : x2);
  u16* out = y == 0 ? o0 : (y == 1 ? o1 : o2);
  long i = ((long)blockIdx.x * 256 + threadIdx.x) * 8;
  f32x4 a = *(const f32x4*)(in + i);
  f32x4 b = *(const f32x4*)(in + i + 4);
  s16x8 o;
#pragma unroll
  for (int j = 0; j < 4; ++j) {
    o[j] = (short)f2h(a[j]);
    o[4 + j] = (short)f2h(b[j]);
  }
  *(s16x8*)(out + i) = o;
}

// W [d][e] f32 -> W^T [e][d] f16, LDS transpose, both sides coalesced.
__global__ __launch_bounds__(256) void wcast_kernel(
    const float* __restrict__ wk, const float* __restrict__ wv,
    const float* __restrict__ wq, u16* __restrict__ ok, u16* __restrict__ ov,
    u16* __restrict__ oq) {
  __shared__ float tile[32][33];
  const int z = blockIdx.z;
  const float* w = z == 0 ? wk : (z == 1 ? wv : wq);
  u16* o = z == 0 ? ok : (z == 1 ? ov : oq);
  const float scale = (z == 2) ? 0.03125f : 1.0f;  // 1/sqrt(1024) into WQ
  const int bx = blockIdx.x, by = blockIdx.y;
  const int lx = threadIdx.x & 31, ly = threadIdx.x >> 5;
#pragma unroll
  for (int j = 0; j < 32; j += 8)
    tile[ly + j][lx] = w[(long)(by * 32 + ly + j) * 1024 + bx * 32 + lx];
  __syncthreads();
#pragma unroll
  for (int j = 0; j < 32; j += 8)
    o[(long)(bx * 32 + ly + j) * 1024 + by * 32 + lx] = f2h(tile[lx][ly + j] * scale);
}

// ---------------- launch ----------------
extern "C" void kernel_launch(void* const* d_in, const int* in_sizes, int n_in,
                              void* d_out, int out_size, void* d_ws, size_t ws_size,
                              hipStream_t stream) {
  const float* Xk = (const float*)d_in[0];
  const float* Xv = (const float*)d_in[1];
  const float* Xq = (const float*)d_in[2];
  const float* WK = (const float*)d_in[3];
  const float* WV = (const float*)d_in[4];
  const float* WQ = (const float*)d_in[5];

  const int Bn = 4, S = 2048, D = 1024;
  const long NX = (long)Bn * S * D;

  const size_t r0 = (size_t)Bn * S * S * 4;
  const size_t r1 = r0 + 3ull * D * D * 2;
  const size_t r2 = r1 + 2ull * NX * 2;
  const size_t NEED = r2 + (size_t)NX * 2;
  if (ws_size < NEED) {
    hipMemsetAsync(d_out, 0, (size_t)out_size * 4, stream);
    return;
  }
  char* ws = (char*)d_ws;
  u16* xkb = (u16*)ws;
  u16* xvb = xkb + NX;
  u16* xqb = xvb + NX;
  u16* scoresH = (u16*)ws;  // aliases dead X after projections
  u16* wkt = (u16*)(ws + r0);
  u16* wvt = wkt + D * D;
  u16* wqt = wvt + D * D;
  u16* Kb = (u16*)(ws + r1);
  u16* Qb = Kb + NX;
  u16* Pb = (u16*)(ws + r1);  // aliases dead K,Q after qkt
  u16* Vt = (u16*)(ws + r2);

  xcast_kernel<<<dim3(4096, 3), 256, 0, stream>>>(Xk, Xv, Xq, xkb, xvb, xqb);
  wcast_kernel<<<dim3(32, 32, 3), 256, 0, stream>>>(WK, WV, WQ, wkt, wvt, wqt);
  proj256_kernel<<<dim3(128, 3), 512, 0, stream>>>(xkb, xqb, xvb, wkt, wqt, wvt,
                                                   Kb, Qb, Vt);
  qkt_kernel<<<dim3(544), 256, 0, stream>>>(Qb, Kb, scoresH);
  softmax_causal<<<dim3(8192), 256, 0, stream>>>(scoresH, Pb);
  pv_kernel<<<dim3(512), 256, 0, stream>>>(Pb, Vt, (float*)d_out);
}

// Round 6
// 163.219 us; speedup vs baseline: 1.0727x; 1.0727x over previous
//
#include <hip/hip_runtime.h>
#include <hip/hip_bf16.h>

typedef unsigned short u16;
typedef _Float16 f16;
typedef __attribute__((ext_vector_type(8))) short s16x8;
typedef __attribute__((ext_vector_type(8))) _Float16 f16x8;
typedef __attribute__((ext_vector_type(4))) float f32x4;
typedef __attribute__((ext_vector_type(4))) unsigned short u16x4;

// ---------------- MFMA wrapper (f16) ----------------
template <typename T>
__device__ __forceinline__ auto mfma_try(T a, T b, f32x4 c, int)
    -> decltype(__builtin_amdgcn_mfma_f32_16x16x32_f16(a, b, c, 0, 0, 0)) {
  return __builtin_amdgcn_mfma_f32_16x16x32_f16(a, b, c, 0, 0, 0);
}
template <typename T>
__device__ __forceinline__ f32x4 mfma_try(T a, T b, f32x4 c, long) {
  return __builtin_amdgcn_mfma_f32_16x16x32_f16(
      __builtin_bit_cast(f16x8, a), __builtin_bit_cast(f16x8, b), c, 0, 0, 0);
}
__device__ __forceinline__ f32x4 MFMA16(s16x8 a, s16x8 b, f32x4 c) {
  return mfma_try(a, b, c, 0);
}

__device__ __forceinline__ void gload16(const void* g, void* s) {
  __builtin_amdgcn_global_load_lds(
      (const __attribute__((address_space(1))) void*)g,
      (__attribute__((address_space(3))) void*)s, 16, 0, 0);
}

__device__ __forceinline__ u16 f2h(float x) {
  f16 h = (f16)x;
  u16 u;
  __builtin_memcpy(&u, &h, 2);
  return u;
}
__device__ __forceinline__ float h2f(u16 u) {
  f16 h;
  __builtin_memcpy(&h, &u, 2);
  return (float)h;
}

#define LDS_SWZ(r, cb) ((cb) ^ (((r)&7) << 4))

// =============== 128x128x64 2-phase dbuf core (proven, ~835 TF) ============
struct Geom {
  int srow[4], scol[4];
  int w, l, wr, wc;
};

__device__ __forceinline__ Geom make_geom() {
  Geom g;
  int tid = threadIdx.x;
  g.w = tid >> 6; g.l = tid & 63;
  g.wr = g.w >> 1; g.wc = g.w & 1;
#pragma unroll
  for (int i = 0; i < 4; ++i) {
    int off = i * 4096 + g.w * 1024 + g.l * 16;
    int r = off >> 7, cb = off & 127;
    g.srow[i] = r;
    g.scol[i] = LDS_SWZ(r, cb) >> 1;  // pre-swizzled global source (rule 21)
  }
  return g;
}

__device__ __forceinline__ void stage(const u16* pan, int ld, int k0,
                                      char* lds, const Geom& g) {
#pragma unroll
  for (int i = 0; i < 4; ++i)
    gload16(pan + (long)g.srow[i] * ld + k0 + g.scol[i],
            lds + i * 4096 + g.w * 1024);
}

__device__ __forceinline__ void compute_step(const char* lA, const char* lB,
                                             const Geom& g, f32x4 acc[4][4]) {
#pragma unroll
  for (int ks = 0; ks < 2; ++ks) {
    s16x8 af[4], bg[4];
#pragma unroll
    for (int m = 0; m < 4; ++m) {
      int r = g.wr * 64 + m * 16 + (g.l & 15);
      int cb = ks * 64 + ((g.l >> 4) << 4);
      af[m] = *(const s16x8*)(lA + r * 128 + LDS_SWZ(r, cb));
    }
#pragma unroll
    for (int n = 0; n < 4; ++n) {
      int r = g.wc * 64 + n * 16 + (g.l & 15);
      int cb = ks * 64 + ((g.l >> 4) << 4);
      bg[n] = *(const s16x8*)(lB + r * 128 + LDS_SWZ(r, cb));
    }
#pragma unroll
    for (int m = 0; m < 4; ++m)
#pragma unroll
      for (int n = 0; n < 4; ++n)
        acc[m][n] = MFMA16(af[m], bg[n], acc[m][n]);
  }
}

// lA/lB each hold 2 buffers of 16 KB at +0 / +16384.
__device__ __forceinline__ void gemm_core(const u16* Apan, int lda,
                                          const u16* Bpan, int ldb, int nsteps,
                                          char* lA, char* lB, const Geom& g,
                                          f32x4 acc[4][4]) {
  stage(Apan, lda, 0, lA, g);
  stage(Bpan, ldb, 0, lB, g);
  __syncthreads();  // drains vmcnt: buf0 ready
  for (int t = 0; t < nsteps; ++t) {
    int cur = (t & 1) << 14;
    if (t + 1 < nsteps) {
      int nxt = ((t + 1) & 1) << 14;
      stage(Apan, lda, (t + 1) * 64, lA + nxt, g);  // prefetch overlaps MFMA
      stage(Bpan, ldb, (t + 1) * 64, lB + nxt, g);
    }
    compute_step(lA + cur, lB + cur, g, acc);
    if (t + 1 < nsteps) __syncthreads();  // one barrier per K-step
  }
}

// ---------------- kernels ----------------
// merged projections: y=0 K, y=1 Q, y=2 V^T. M folded over batch (8192).
__global__ __launch_bounds__(256, 2) void proj_kernel(
    const u16* __restrict__ xk, const u16* __restrict__ xq, const u16* __restrict__ xv,
    const u16* __restrict__ wk, const u16* __restrict__ wq, const u16* __restrict__ wv,
    u16* __restrict__ K, u16* __restrict__ Q, u16* __restrict__ Vt) {
  __shared__ char lds[65536];
  const int y = blockIdx.y;
  const u16* X = y == 0 ? xk : (y == 1 ? xq : xv);
  const u16* W = y == 0 ? wk : (y == 1 ? wq : wv);
  const int bx = blockIdx.x;
  const int swz = (bx & 7) * 64 + (bx >> 3);  // 512 blocks, bijective
  const int tm = swz >> 3, tn = swz & 7;
  Geom g = make_geom();
  f32x4 acc[4][4] = {};
  gemm_core(X + (long)tm * 128 * 1024, 1024, W + (long)tn * 128 * 1024, 1024,
            16, lds, lds + 32768, g, acc);
  const int rg0 = tm * 128 + g.wr * 64, cg0 = tn * 128 + g.wc * 64;
  if (y < 2) {
    u16* C = y == 0 ? K : Q;
#pragma unroll
    for (int m = 0; m < 4; ++m)
#pragma unroll
      for (int n = 0; n < 4; ++n)
#pragma unroll
        for (int j = 0; j < 4; ++j) {
          int rg = rg0 + m * 16 + ((g.l >> 4) << 2) + j;
          int cg = cg0 + n * 16 + (g.l & 15);
          C[(long)rg * 1024 + cg] = f2h(acc[m][n][j]);
        }
  } else {
#pragma unroll
    for (int m = 0; m < 4; ++m) {
      int rg = rg0 + m * 16 + ((g.l >> 4) << 2);
      int b = rg >> 11, rl = rg & 2047;
#pragma unroll
      for (int n = 0; n < 4; ++n) {
        int cg = cg0 + n * 16 + (g.l & 15);
        u16x4 pk;
#pragma unroll
        for (int j = 0; j < 4; ++j) pk[j] = f2h(acc[m][n][j]);
        *(u16x4*)(Vt + (long)b * (1024 * 2048) + (long)cg * 2048 + rl) = pk;
      }
    }
  }
}

// scores = Q K^T, triangular tile grid, f16 out. 544 blocks (4 batches x 136).
__global__ __launch_bounds__(256, 2) void qkt_kernel(
    const u16* __restrict__ Q, const u16* __restrict__ K, u16* __restrict__ S) {
  __shared__ char lds[65536];
  const int bx = blockIdx.x;
  const int swz = (bx & 7) * 68 + (bx >> 3);  // 544 = 8*68, bijective
  const int b = swz / 136;
  int t = swz - b * 136;
  int tm = 0;
  while (t > tm) { t -= tm + 1; ++tm; }
  const int tn = t;
  Geom g = make_geom();
  f32x4 acc[4][4] = {};
  const u16* Qb = Q + (long)b * 2048 * 1024;
  const u16* Kb = K + (long)b * 2048 * 1024;
  gemm_core(Qb + (long)tm * 128 * 1024, 1024, Kb + (long)tn * 128 * 1024, 1024,
            16, lds, lds + 32768, g, acc);
  u16* Sb = S + (long)b * 2048 * 2048;
  const int rg0 = tm * 128 + g.wr * 64, cg0 = tn * 128 + g.wc * 64;
#pragma unroll
  for (int m = 0; m < 4; ++m)
#pragma unroll
    for (int n = 0; n < 4; ++n)
#pragma unroll
      for (int j = 0; j < 4; ++j) {
        int rg = rg0 + m * 16 + ((g.l >> 4) << 2) + j;
        int cg = cg0 + n * 16 + (g.l & 15);
        Sb[(long)rg * 2048 + cg] = f2h(acc[m][n][j]);
      }
}

// O = P V (k-limited), f32 out. 512 blocks.
__global__ __launch_bounds__(256, 2) void pv_kernel(
    const u16* __restrict__ P, const u16* __restrict__ Vt, float* __restrict__ O) {
  __shared__ char lds[65536];
  const int bx = blockIdx.x;
  const int swz = (bx & 7) * 64 + (bx >> 3);
  const int b = swz >> 7, loc = swz & 127;
  const int tm = loc >> 3, tn = loc & 7;
  Geom g = make_geom();
  f32x4 acc[4][4] = {};
  gemm_core(P + ((long)b * 2048 + tm * 128) * 2048, 2048,
            Vt + (long)b * 1024 * 2048 + (long)tn * 128 * 2048, 2048,
            (tm + 1) * 2, lds, lds + 32768, g, acc);
  const int rg0 = tm * 128 + g.wr * 64, cg0 = tn * 128 + g.wc * 64;
#pragma unroll
  for (int m = 0; m < 4; ++m)
#pragma unroll
    for (int n = 0; n < 4; ++n)
#pragma unroll
      for (int j = 0; j < 4; ++j) {
        int rg = rg0 + m * 16 + ((g.l >> 4) << 2) + j;
        int cg = cg0 + n * 16 + (g.l & 15);
        O[((long)b * 2048 + rg) * 1024 + cg] = acc[m][n][j];
      }
}

// ---------------- causal softmax: f16 scores -> f16 P ----------------
// Threads fully above the diagonal skip the global READ (write zeros only):
// read traffic ~halves on the triangular score matrix.
__global__ __launch_bounds__(256) void softmax_causal(
    const u16* __restrict__ S, u16* __restrict__ P) {
  const int row = blockIdx.x;  // b*2048 + i
  const int i_q = row & 2047;
  const u16* sr = S + (long)row * 2048;
  u16* pr = P + (long)row * 2048;
  const int tid = threadIdx.x;
  const int l = tid & 63, w = tid >> 6;
  const int base = tid * 8;

  float v[8];
  float m = -INFINITY;
  if (base <= i_q) {  // at least one valid element in this chunk
    s16x8 raw = *(const s16x8*)(sr + base);
#pragma unroll
    for (int j = 0; j < 8; ++j) {
      float x = h2f((u16)raw[j]);
      x = (base + j <= i_q) ? x : -INFINITY;
      v[j] = x;
      m = fmaxf(m, x);
    }
  } else {
#pragma unroll
    for (int j = 0; j < 8; ++j) v[j] = -INFINITY;
  }
  __shared__ float red[8];
  for (int o = 32; o; o >>= 1) m = fmaxf(m, __shfl_xor(m, o, 64));
  if (l == 0) red[w] = m;
  __syncthreads();
  m = fmaxf(fmaxf(red[0], red[1]), fmaxf(red[2], red[3]));

  float s = 0.f;
#pragma unroll
  for (int j = 0; j < 8; ++j) {
    v[j] = expf(v[j] - m);  // exp(-inf - m) = 0 for masked
    s += v[j];
  }
  for (int o = 32; o; o >>= 1) s += __shfl_xor(s, o, 64);
  if (l == 0) red[4 + w] = s;
  __syncthreads();
  s = (red[4] + red[5]) + (red[6] + red[7]);
  float inv = 1.0f / s;

  s16x8 o;
#pragma unroll
  for (int j = 0; j < 8; ++j) o[j] = (short)f2h(v[j] * inv);
  *(s16x8*)(pr + base) = o;
}

// ---------------- merged casts (one dispatch) ----------------
// blocks [0,12288): X casts (y = bid/4096).  blocks [12288,15360): W^T casts.
__global__ __launch_bounds__(256) void cast_all_kernel(
    const float* __restrict__ x0, const float* __restrict__ x1,
    const float* __restrict__ x2, u16* __restrict__ o0, u16* __restrict__ o1,
    u16* __restrict__ o2, const float* __restrict__ wk,
    const float* __restrict__ wv, const float* __restrict__ wq,
    u16* __restrict__ ok, u16* __restrict__ ov, u16* __restrict__ oq) {
  const int bid = blockIdx.x;
  if (bid < 12288) {
    const int y = bid >> 12;  // /4096
    const float* in = y == 0 ? x0 : (y == 1 ? x1 : x2);
    u16* out = y == 0 ? o0 : (y == 1 ? o1 : o2);
    long i = ((long)(bid & 4095) * 256 + threadIdx.x) * 8;
    f32x4 a = *(const f32x4*)(in + i);
    f32x4 b = *(const f32x4*)(in + i + 4);
    s16x8 o;
#pragma unroll
    for (int j = 0; j < 4; ++j) {
      o[j] = (short)f2h(a[j]);
      o[4 + j] = (short)f2h(b[j]);
    }
    *(s16x8*)(out + i) = o;
  } else {
    __shared__ float tile[32][33];
    const int t = bid - 12288;
    const int z = t >> 10;             // /1024
    const int loc = t & 1023;
    const int bx = loc & 31, by = loc >> 5;
    const float* w = z == 0 ? wk : (z == 1 ? wv : wq);
    u16* o = z == 0 ? ok : (z == 1 ? ov : oq);
    const float scale = (z == 2) ? 0.03125f : 1.0f;  // 1/sqrt(1024) into WQ
    const int lx = threadIdx.x & 31, ly = threadIdx.x >> 5;
#pragma unroll
    for (int j = 0; j < 32; j += 8)
      tile[ly + j][lx] = w[(long)(by * 32 + ly + j) * 1024 + bx * 32 + lx];
    __syncthreads();
#pragma unroll
    for (int j = 0; j < 32; j += 8)
      o[(long)(bx * 32 + ly + j) * 1024 + by * 32 + lx] =
          f2h(tile[lx][ly + j] * scale);
  }
}

// ---------------- launch ----------------
extern "C" void kernel_launch(void* const* d_in, const int* in_sizes, int n_in,
                              void* d_out, int out_size, void* d_ws, size_t ws_size,
                              hipStream_t stream) {
  const float* Xk = (const float*)d_in[0];
  const float* Xv = (const float*)d_in[1];
  const float* Xq = (const float*)d_in[2];
  const float* WK = (const float*)d_in[3];
  const float* WV = (const float*)d_in[4];
  const float* WQ = (const float*)d_in[5];

  const int Bn = 4, S = 2048, D = 1024;
  const long NX = (long)Bn * S * D;

  // ws layout (aliasing):
  //  region0 [0,64MB): Xk,Xv,Xq f16 (50.3MB) -> later scores f16 (32MB)
  //  region1: WKt,WVt,WQt f16 (6MB)
  //  region2: K,Q f16 (32MB) -> later P f16 (32MB)
  //  region3: V^T f16 (16MB)
  const size_t r0 = (size_t)Bn * S * S * 4;
  const size_t r1 = r0 + 3ull * D * D * 2;
  const size_t r2 = r1 + 2ull * NX * 2;
  const size_t NEED = r2 + (size_t)NX * 2;
  if (ws_size < NEED) {
    hipMemsetAsync(d_out, 0, (size_t)out_size * 4, stream);
    return;
  }
  char* ws = (char*)d_ws;
  u16* xkb = (u16*)ws;
  u16* xvb = xkb + NX;
  u16* xqb = xvb + NX;
  u16* scoresH = (u16*)ws;  // aliases dead X after projections
  u16* wkt = (u16*)(ws + r0);
  u16* wvt = wkt + D * D;
  u16* wqt = wvt + D * D;
  u16* Kb = (u16*)(ws + r1);
  u16* Qb = Kb + NX;
  u16* Pb = (u16*)(ws + r1);  // aliases dead K,Q after qkt
  u16* Vt = (u16*)(ws + r2);

  cast_all_kernel<<<dim3(15360), 256, 0, stream>>>(Xk, Xv, Xq, xkb, xvb, xqb,
                                                   WK, WV, WQ, wkt, wvt, wqt);
  proj_kernel<<<dim3(512, 3), 256, 0, stream>>>(xkb, xqb, xvb, wkt, wqt, wvt,
                                                Kb, Qb, Vt);
  qkt_kernel<<<dim3(544), 256, 0, stream>>>(Qb, Kb, scoresH);
  softmax_causal<<<dim3(8192), 256, 0, stream>>>(scoresH, Pb);
  pv_kernel<<<dim3(512), 256, 0, stream>>>(Pb, Vt, (float*)d_out);
}